// Round 6
// baseline (146.818 us; speedup 1.0000x reference)
//
#include <hip/hip_runtime.h>

// DotProductAttention: B=16, NQ=2048, NK=2048, D=128, DV=128, fp32 in/out.
// R12: halve LDS traffic at constant wave count, zero duplicated work.
// Model: R7 (49us) sits on its LDS-read budget (128 ds_read_b128/blk-tile
// ~= 3580cy/CU/tile-pair == measured). R8 cut reads but halved waves (lat-
// bound); R11 kept waves but duplicated QK+softmax (VALU-bloat). R12:
// 8 waves = 2wq(32q, two q16 ILP chains) x 4wk(16 keys). Per wave: K 4KB,
// V 4KB -> 32 b128 + 64 b64 per blk-tile (~half the LDS cycles).
// Enabler: with 16 keys/wave PV uses mfma_f32_16x16x16_bf16 whose A-frag
// layout (m=lane&15, k=quad*4+j) EQUALS the QK^T C-layout -> P feeds PV
// directly; permlanes eliminated; softmax VALU halves. 4-quarter O combine
// via two-phase LDS add in the (per-task) epilogue. Everything else = R7/R10.

#define B_   16
#define NQ_  2048
#define NK_  2048
#define D_   128
#define DV_  128
#define NTASK_ 512

typedef unsigned short ushort;
typedef __attribute__((ext_vector_type(4))) float          f32x4;
typedef __attribute__((ext_vector_type(8))) __bf16         bf16x8;
typedef __attribute__((ext_vector_type(8))) unsigned short ushort8v;
typedef __attribute__((ext_vector_type(4))) unsigned short ushort4v;
typedef __attribute__((ext_vector_type(4))) short          short4v;
typedef __attribute__((ext_vector_type(4))) unsigned int   uint4v;
typedef __attribute__((ext_vector_type(2))) unsigned int   uint2v;

#ifdef __has_builtin
#if __has_builtin(__builtin_amdgcn_cvt_pk_bf16_f32)
#define HAVE_CVT_PK_BF16 1
#endif
#if __has_builtin(__builtin_amdgcn_mfma_f32_16x16x16bf16_1k)
#define HAVE_MFMA16_1K 1
#endif
#endif

__device__ __forceinline__ ushort f2bf(float f) {
    unsigned u = __builtin_bit_cast(unsigned, f);
    return (ushort)((u + 0x8000u) >> 16);
}
__device__ __forceinline__ unsigned f2bf2(float a, float b) {
#ifdef HAVE_CVT_PK_BF16
    auto t = __builtin_amdgcn_cvt_pk_bf16_f32(a, b);
    return __builtin_bit_cast(unsigned, t);
#else
    return (unsigned)f2bf(a) | ((unsigned)f2bf(b) << 16);
#endif
}
// sum of the two bf16 values packed in u (exactly the values PV consumes)
__device__ __forceinline__ float bfpair_sum(unsigned u) {
    float lo = __builtin_bit_cast(float, u << 16);
    float hi = __builtin_bit_cast(float, u & 0xffff0000u);
    return lo + hi;
}
__device__ __forceinline__ void gl_lds16(const ushort* g, ushort* l) {
    __builtin_amdgcn_global_load_lds(
        (const __attribute__((address_space(1))) void*)g,
        (__attribute__((address_space(3))) void*)l, 16, 0, 0);
}
// 16x16x16 bf16 MFMA (K=16): builtin if present, else raw encoding via asm.
__device__ __forceinline__ f32x4 mfma16(short4v a, short4v b, f32x4 c) {
#ifdef HAVE_MFMA16_1K
    return __builtin_amdgcn_mfma_f32_16x16x16bf16_1k(a, b, c, 0, 0, 0);
#else
    asm("v_mfma_f32_16x16x16_bf16 %0, %1, %2, %0" : "+v"(c) : "v"(a), "v"(b));
    return c;
#endif
}

// Pre-pass: per (b, k-tile): K -> bf16 tile [key64][d128], 16B-unit swizzle
// (d-unit du stored at du ^ (key&7)); V -> bf16 transposed [dv128][key64],
// key-unit kg stored at kg ^ (dv&7). V transposed via LDS (R10). Unchanged.
#define VL_STRIDE 132
__global__ __launch_bounds__(256) void convert_kv(
    const float* __restrict__ K, const float* __restrict__ V,
    const int* __restrict__ vlen, ushort* __restrict__ Kb, ushort* __restrict__ Vtb)
{
    __shared__ ushort Vl[64 * VL_STRIDE];   // 16.5 KB
    const int id = blockIdx.x;              // 512 = 16 b x 32 tiles
    const int b  = id & 15, kt = id >> 4;
    if (kt >= ((vlen[b] + 63) >> 6)) return;
    const int tid = threadIdx.x;
    const float* gK = K + ((size_t)b * NK_ + kt * 64) * D_;
    const float* gV = V + ((size_t)b * NK_ + kt * 64) * DV_;
    ushort* tK = Kb  + ((size_t)b * 32 + kt) * 8192;
    ushort* tV = Vtb + ((size_t)b * 32 + kt) * 8192;

    #pragma unroll
    for (int i = 0; i < 4; ++i) {           // 1024 K units: key = u>>4, d-unit = u&15
        int u = i * 256 + tid;
        int key = u >> 4, d8 = u & 15;
        const float* p = gK + key * D_ + d8 * 8;
        f32x4 a0 = *(const f32x4*)p;
        f32x4 a1 = *(const f32x4*)(p + 4);
        uint4v w;
        w[0] = f2bf2(a0[0], a0[1]); w[1] = f2bf2(a0[2], a0[3]);
        w[2] = f2bf2(a1[0], a1[1]); w[3] = f2bf2(a1[2], a1[3]);
        *(uint4v*)&tK[key * 128 + ((d8 ^ (key & 7)) << 3)] = w;
    }

    // ---- V phase 1: coalesced row loads -> bf16 -> LDS [64][VL_STRIDE]
    #pragma unroll
    for (int i = 0; i < 4; ++i) {
        int u = i * 256 + tid;
        int key = u >> 4, d8 = u & 15;
        const float* p = gV + key * DV_ + d8 * 8;
        f32x4 a0 = *(const f32x4*)p;
        f32x4 a1 = *(const f32x4*)(p + 4);
        uint4v w;
        w[0] = f2bf2(a0[0], a0[1]); w[1] = f2bf2(a0[2], a0[3]);
        w[2] = f2bf2(a1[0], a1[1]); w[3] = f2bf2(a1[2], a1[3]);
        *(uint4v*)&Vl[key * VL_STRIDE + d8 * 8] = w;
    }
    __syncthreads();

    // ---- V phase 2: column gather from LDS, coalesced 16B writes to tV.
    #pragma unroll
    for (int i = 0; i < 4; ++i) {
        int u  = i * 256 + tid;             // 1024 units: c = u&7, dv = u>>3
        int c  = u & 7, dv = u >> 3;
        int kg = c ^ (dv & 7);
        ushort v[8];
        #pragma unroll
        for (int j = 0; j < 8; ++j) v[j] = Vl[(kg * 8 + j) * VL_STRIDE + dv];
        uint4v w;
        w[0] = (unsigned)v[0] | ((unsigned)v[1] << 16);
        w[1] = (unsigned)v[2] | ((unsigned)v[3] << 16);
        w[2] = (unsigned)v[4] | ((unsigned)v[5] << 16);
        w[3] = (unsigned)v[6] | ((unsigned)v[7] << 16);
        *(uint4v*)&tV[dv * 64 + c * 8] = w;
    }
}

__global__ __launch_bounds__(512, 4) void attn_fwd(
    const float* __restrict__ Q, const int* __restrict__ vlen,
    const ushort* __restrict__ Kb, const ushort* __restrict__ Vtb,
    float* __restrict__ Out)
{
    // double-buffered K|V tiles (bf16, swizzled): [buf][ K 8192 | V 8192 ]
    __shared__ ushort KVbuf[2][16384];                 // 64 KB
    __shared__ float  lsh[4][64];
    __shared__ int    ssch[16];
    float* Osh = (float*)&KVbuf[0][0];                 // epilogue alias: [2][64q][128dv]

    const int tid  = threadIdx.x;     // 0..511
    const int w    = tid >> 6;        // 0..7
    const int wq   = w >> 2;          // 0..1 : 32 q-rows (two q16 chains)
    const int wk   = w & 3;           // 0..3 : 16-key quarter
    const int L    = tid & 63;
    const int col  = L & 15;
    const int quad = L >> 4;

    // ---- inline schedule: rank batches by vl desc
    if (tid < 16) {
        int my = vlen[tid];
        int rank = 0;
        for (int o = 0; o < 16; ++o) {
            int vo = vlen[o];
            if (vo > my || (vo == my && o < tid)) ++rank;
        }
        ssch[rank] = tid;
    }
    __syncthreads();

    // ---- R7 decode (no XCD pinning; R10 A/B showed pinning costs 5us)
    const int e     = blockIdx.x;
    const int p_    = (e & 255) >> 5;
    const int b     = (e >> 8) ? ssch[15 - p_] : ssch[p_];
    const int qbase = (e & 31) * 64;
    const int vl    = vlen[b];
    const int ntiles = (vl + 63) >> 6;

    // ---- Q fragments: 2 x q16 (32 rows/wave), pre-scaled by log2(e)/sqrt(128)
    const float qscale = 0.12751743f;
    bf16x8 qf[2][4];
    #pragma unroll
    for (int q16 = 0; q16 < 2; ++q16) {
        const int qrow = qbase + wq * 32 + q16 * 16 + col;
        const float* gQ = Q + ((size_t)b * NQ_ + qrow) * D_;
        #pragma unroll
        for (int c = 0; c < 4; ++c) {
            const float* pp = gQ + c * 32 + quad * 8;
            f32x4 a0 = *(const f32x4*)pp;
            f32x4 a1 = *(const f32x4*)(pp + 4);
            uint4v us;
            us[0] = f2bf2(a0[0] * qscale, a0[1] * qscale);
            us[1] = f2bf2(a0[2] * qscale, a0[3] * qscale);
            us[2] = f2bf2(a1[0] * qscale, a1[1] * qscale);
            us[3] = f2bf2(a1[2] * qscale, a1[3] * qscale);
            qf[q16][c] = __builtin_bit_cast(bf16x8, us);
        }
    }

    // ---- accumulators: partial O over own 16-key quarter, full 128 dv
    f32x4 o[2][8];
    #pragma unroll
    for (int q16 = 0; q16 < 2; ++q16)
        #pragma unroll
        for (int d = 0; d < 8; ++d) o[q16][d] = (f32x4){0.f, 0.f, 0.f, 0.f};
    float l_run[2] = {0.f, 0.f};

    const ushort* tKb = Kb  + (size_t)b * 32 * 8192;
    const ushort* tVb = Vtb + (size_t)b * 32 * 8192;

    #define ISSUE_DMA(KT, BUF)                                               \
        do {                                                                 \
            const ushort* gk = tKb + (size_t)(KT) * 8192;                    \
            const ushort* gv = tVb + (size_t)(KT) * 8192;                    \
            _Pragma("unroll")                                                \
            for (int i = 0; i < 2; ++i) {                                    \
                int off = (i * 512 + tid) * 8;                               \
                gl_lds16(gk + off, &KVbuf[BUF][off]);                        \
                gl_lds16(gv + off, &KVbuf[BUF][8192 + off]);                 \
            }                                                                \
        } while (0)

    ISSUE_DMA(0, 0);

    const int swz = col & 7;
    // V b64 read: key-unit kg = wk*2 + (quad>>1), sub-offset (quad&1)*4
    const int vkg  = wk * 2 + (quad >> 1);
    const int vsub = (quad & 1) * 4;

    for (int kt = 0; kt < ntiles; ++kt) {
        const int buf = kt & 1;
        __syncthreads();   // drains DMA(kt); prev readers done
        if (kt + 1 < ntiles) ISSUE_DMA(kt + 1, buf ^ 1);

        const ushort* Kt = &KVbuf[buf][0];
        const ushort* Vt = &KVbuf[buf][8192];

        // ---- S^T = K Q^T (swapped): A = own 16 keys (m=lane&15=key),
        // lane holds S[q=col][key = quad*4 + r]. K frags feed both q16 chains.
        f32x4 s[2];
        s[0] = (f32x4){0.f,0.f,0.f,0.f};
        s[1] = (f32x4){0.f,0.f,0.f,0.f};
        __builtin_amdgcn_s_setprio(1);
        {
            const int kbase = (wk * 16 + col) * 128;
            #pragma unroll
            for (int c = 0; c < 4; ++c) {
                bf16x8 kb = __builtin_bit_cast(bf16x8, *(const ushort8v*)
                    &Kt[kbase + (((c * 4 + quad) ^ swz) << 3)]);
                s[0] = __builtin_amdgcn_mfma_f32_16x16x32_bf16(kb, qf[0][c], s[0], 0, 0, 0);
                s[1] = __builtin_amdgcn_mfma_f32_16x16x32_bf16(kb, qf[1][c], s[1], 0, 0, 0);
            }
        }
        __builtin_amdgcn_s_setprio(0);

        // ---- mask own quarter; exp2(-1e30) == 0
        const int rem = vl - kt * 64 - wk * 16;   // valid keys in this quarter
        if (rem < 16) {
            #pragma unroll
            for (int rr = 0; rr < 4; ++rr)
                if (quad * 4 + rr >= rem) { s[0][rr] = -1e30f; s[1][rr] = -1e30f; }
        }

        // ---- p = exp2(s): C-layout (q=col, k=quad*4+r) IS the 16x16x16
        // A-frag layout (m=lane&15, k=quad*4+j) -> direct feed, no permlane.
        short4v pa[2];
        #pragma unroll
        for (int q16 = 0; q16 < 2; ++q16) {
            unsigned w0 = f2bf2(exp2f(s[q16][0]), exp2f(s[q16][1]));
            unsigned w1 = f2bf2(exp2f(s[q16][2]), exp2f(s[q16][3]));
            l_run[q16] += bfpair_sum(w0) + bfpair_sum(w1);
            uint2v t; t[0] = w0; t[1] = w1;
            pa[q16] = __builtin_bit_cast(short4v, t);
        }

        // ---- O_partial += P(32q x 16k) V(16k x 128dv), K=16 MFMA
        __builtin_amdgcn_s_setprio(1);
        #pragma unroll
        for (int dvc = 0; dvc < 8; ++dvc) {
            const int dv = dvc * 16 + col;
            short4v vb = __builtin_bit_cast(short4v, *(const ushort4v*)
                &Vt[dv * 64 + ((vkg ^ (dv & 7)) << 3) + vsub]);
            o[0][dvc] = mfma16(pa[0], vb, o[0][dvc]);
            o[1][dvc] = mfma16(pa[1], vb, o[1][dvc]);
        }
        __builtin_amdgcn_s_setprio(0);
    }
    #undef ISSUE_DMA

    // ---- l: sum the 4 quads holding the same q=col
    #pragma unroll
    for (int q16 = 0; q16 < 2; ++q16) {
        l_run[q16] += __shfl_xor(l_run[q16], 16, 64);
        l_run[q16] += __shfl_xor(l_run[q16], 32, 64);
    }

    __syncthreads();   // everyone done with KVbuf before aliasing as Osh

    if (L < 16) {
        lsh[wk][wq * 32 + L]      = l_run[0];
        lsh[wk][wq * 32 + 16 + L] = l_run[1];
    }
    // ---- phase A: quarters 0,1 write their partial O
    if (wk < 2) {
        #pragma unroll
        for (int q16 = 0; q16 < 2; ++q16)
            #pragma unroll
            for (int dvc = 0; dvc < 8; ++dvc)
                #pragma unroll
                for (int rr = 0; rr < 4; ++rr)
                    Osh[wk * 8192 + (wq * 32 + q16 * 16 + quad * 4 + rr) * 128
                        + dvc * 16 + col] = o[q16][dvc][rr];
    }
    __syncthreads();
    // ---- phase B: quarters 2,3 accumulate in place
    if (wk >= 2) {
        #pragma unroll
        for (int q16 = 0; q16 < 2; ++q16)
            #pragma unroll
            for (int dvc = 0; dvc < 8; ++dvc)
                #pragma unroll
                for (int rr = 0; rr < 4; ++rr)
                    Osh[(wk - 2) * 8192 + (wq * 32 + q16 * 16 + quad * 4 + rr) * 128
                        + dvc * 16 + col] += o[q16][dvc][rr];
    }
    __syncthreads();

    // ---- combine halves, normalize, coalesced store
    float* gO = Out + ((size_t)b * NQ_ + qbase) * DV_;
    #pragma unroll
    for (int i = 0; i < 4; ++i) {
        int idx = i * 512 + tid;           // f32x4 chunk id, row-major
        int row = idx >> 5;
        int dq  = idx & 31;
        f32x4 a0 = *(const f32x4*)&Osh[row * 128 + dq * 4];
        f32x4 a1 = *(const f32x4*)&Osh[8192 + row * 128 + dq * 4];
        float linv = 1.0f / (lsh[0][row] + lsh[1][row] + lsh[2][row] + lsh[3][row]);
        *(f32x4*)&gO[(size_t)row * DV_ + dq * 4] = (a0 + a1) * linv;
    }
}

extern "C" void kernel_launch(void* const* d_in, const int* in_sizes, int n_in,
                              void* d_out, int out_size, void* d_ws, size_t ws_size,
                              hipStream_t stream) {
    const float* Q  = (const float*)d_in[0];
    const float* K  = (const float*)d_in[1];
    const float* V  = (const float*)d_in[2];
    const int*   vl = (const int*)d_in[3];
    float* out = (float*)d_out;

    // ws: [0,4K) reserved | [4K, +8.39M) Kb | [next, +8.39M) Vtb  (~16.8 MB)
    char* ws = (char*)d_ws;
    ushort* Kbuf = (ushort*)(ws + 4096);
    ushort* Vbuf = Kbuf + (size_t)B_ * 32 * 8192;

    convert_kv<<<dim3(512, 1, 1), dim3(256, 1, 1), 0, stream>>>(K, V, vl, Kbuf, Vbuf);
    attn_fwd<<<dim3(NTASK_, 1, 1), dim3(512, 1, 1), 0, stream>>>(
        Q, vl, Kbuf, Vbuf, out);
}

// Round 8
// 132.568 us; speedup vs baseline: 1.1075x; 1.1075x over previous
//
#include <hip/hip_runtime.h>

// DotProductAttention: B=16, NQ=2048, NK=2048, D=128, DV=128, fp32 in/out.
// R13 (resubmit; R7 bench was an infra failure, not a kernel failure).
// attn_fwd = R7 EXACTLY (best measured, 49.2us: 512thr, 8 waves x 16q,
// in-reg P via swapped QK^T + cvt_pk + permlane, 64KB dbuf KV, rank-pair
// decode, NO XCD pinning). convert_kv = R10's LDS-transpose version (proven
// -2.5us vs strided). Structural variants R8/R9/R11/R12 all regressed
// (55.7 / 301 / 67.4 / 65.0); this combo was never benched together.

#define B_   16
#define NQ_  2048
#define NK_  2048
#define D_   128
#define DV_  128
#define NTASK_ 512

typedef unsigned short ushort;
typedef __attribute__((ext_vector_type(4))) float          f32x4;
typedef __attribute__((ext_vector_type(8))) __bf16         bf16x8;
typedef __attribute__((ext_vector_type(8))) unsigned short ushort8v;
typedef __attribute__((ext_vector_type(4))) unsigned int   uint4v;

#ifdef __has_builtin
#if __has_builtin(__builtin_amdgcn_cvt_pk_bf16_f32)
#define HAVE_CVT_PK_BF16 1
#endif
#endif

__device__ __forceinline__ ushort f2bf(float f) {
    unsigned u = __builtin_bit_cast(unsigned, f);
    return (ushort)((u + 0x8000u) >> 16);
}
__device__ __forceinline__ unsigned f2bf2(float a, float b) {
#ifdef HAVE_CVT_PK_BF16
    auto t = __builtin_amdgcn_cvt_pk_bf16_f32(a, b);
    return __builtin_bit_cast(unsigned, t);
#else
    return (unsigned)f2bf(a) | ((unsigned)f2bf(b) << 16);
#endif
}
// sum of the two bf16 values packed in u (exactly the values PV consumes)
__device__ __forceinline__ float bfpair_sum(unsigned u) {
    float lo = __builtin_bit_cast(float, u << 16);
    float hi = __builtin_bit_cast(float, u & 0xffff0000u);
    return lo + hi;
}
__device__ __forceinline__ void gl_lds16(const ushort* g, ushort* l) {
    __builtin_amdgcn_global_load_lds(
        (const __attribute__((address_space(1))) void*)g,
        (__attribute__((address_space(3))) void*)l, 16, 0, 0);
}

// Pre-pass: per (b, k-tile): K -> bf16 tile [key64][d128], 16B-unit swizzle
// (d-unit du stored at du ^ (key&7)); V -> bf16 transposed [dv128][key64],
// key-unit kg stored at kg ^ (dv&7). V transposed via LDS (R10 version).
#define VL_STRIDE 132
__global__ __launch_bounds__(256) void convert_kv(
    const float* __restrict__ K, const float* __restrict__ V,
    const int* __restrict__ vlen, ushort* __restrict__ Kb, ushort* __restrict__ Vtb)
{
    __shared__ ushort Vl[64 * VL_STRIDE];   // 16.5 KB
    const int id = blockIdx.x;              // 512 = 16 b x 32 tiles
    const int b  = id & 15, kt = id >> 4;
    if (kt >= ((vlen[b] + 63) >> 6)) return;
    const int tid = threadIdx.x;
    const float* gK = K + ((size_t)b * NK_ + kt * 64) * D_;
    const float* gV = V + ((size_t)b * NK_ + kt * 64) * DV_;
    ushort* tK = Kb  + ((size_t)b * 32 + kt) * 8192;
    ushort* tV = Vtb + ((size_t)b * 32 + kt) * 8192;

    #pragma unroll
    for (int i = 0; i < 4; ++i) {           // 1024 K units: key = u>>4, d-unit = u&15
        int u = i * 256 + tid;
        int key = u >> 4, d8 = u & 15;
        const float* p = gK + key * D_ + d8 * 8;
        f32x4 a0 = *(const f32x4*)p;
        f32x4 a1 = *(const f32x4*)(p + 4);
        uint4v w;
        w[0] = f2bf2(a0[0], a0[1]); w[1] = f2bf2(a0[2], a0[3]);
        w[2] = f2bf2(a1[0], a1[1]); w[3] = f2bf2(a1[2], a1[3]);
        *(uint4v*)&tK[key * 128 + ((d8 ^ (key & 7)) << 3)] = w;
    }

    // ---- V phase 1: coalesced row loads -> bf16 -> LDS [64][VL_STRIDE]
    #pragma unroll
    for (int i = 0; i < 4; ++i) {
        int u = i * 256 + tid;
        int key = u >> 4, d8 = u & 15;
        const float* p = gV + key * DV_ + d8 * 8;
        f32x4 a0 = *(const f32x4*)p;
        f32x4 a1 = *(const f32x4*)(p + 4);
        uint4v w;
        w[0] = f2bf2(a0[0], a0[1]); w[1] = f2bf2(a0[2], a0[3]);
        w[2] = f2bf2(a1[0], a1[1]); w[3] = f2bf2(a1[2], a1[3]);
        *(uint4v*)&Vl[key * VL_STRIDE + d8 * 8] = w;
    }
    __syncthreads();

    // ---- V phase 2: column gather from LDS, coalesced 16B writes to tV.
    #pragma unroll
    for (int i = 0; i < 4; ++i) {
        int u  = i * 256 + tid;             // 1024 units: c = u&7, dv = u>>3
        int c  = u & 7, dv = u >> 3;
        int kg = c ^ (dv & 7);
        ushort v[8];
        #pragma unroll
        for (int j = 0; j < 8; ++j) v[j] = Vl[(kg * 8 + j) * VL_STRIDE + dv];
        uint4v w;
        w[0] = (unsigned)v[0] | ((unsigned)v[1] << 16);
        w[1] = (unsigned)v[2] | ((unsigned)v[3] << 16);
        w[2] = (unsigned)v[4] | ((unsigned)v[5] << 16);
        w[3] = (unsigned)v[6] | ((unsigned)v[7] << 16);
        *(uint4v*)&tV[dv * 64 + c * 8] = w;
    }
}

__global__ __launch_bounds__(512, 4) void attn_fwd(
    const float* __restrict__ Q, const int* __restrict__ vlen,
    const ushort* __restrict__ Kb, const ushort* __restrict__ Vtb,
    float* __restrict__ Out)
{
    // double-buffered K|V tiles (bf16, swizzled): [buf][ K 8192 | V 8192 ]
    __shared__ ushort KVbuf[2][16384];                 // 64 KB
    __shared__ float  lsh[2][64];
    __shared__ int    ssch[16];
    float* Osh = (float*)&KVbuf[0][0];                 // epilogue alias: [wk][64q][128dv]

    const int tid  = threadIdx.x;     // 0..511
    const int w    = tid >> 6;        // 0..7
    const int wq   = w >> 1;          // q-sixteenth owner (16 rows)
    const int wk   = w & 1;           // key-half (32 keys)
    const int L    = tid & 63;
    const int col  = L & 15;
    const int quad = L >> 4;

    // ---- inline schedule: rank batches by vl desc
    if (tid < 16) {
        int my = vlen[tid];
        int rank = 0;
        for (int o = 0; o < 16; ++o) {
            int vo = vlen[o];
            if (vo > my || (vo == my && o < tid)) ++rank;
        }
        ssch[rank] = tid;
    }
    __syncthreads();

    // ---- R7 decode: pair rank p with 15-p; halves e and e+256.
    const int e     = blockIdx.x;
    const int p_    = (e & 255) >> 5;
    const int b     = (e >> 8) ? ssch[15 - p_] : ssch[p_];
    const int qbase = (e & 31) * 64;
    const int vl    = vlen[b];
    const int ntiles = (vl + 63) >> 6;

    // ---- Q fragments (16 rows/wave), pre-scaled by log2(e)/sqrt(128)
    const float qscale = 0.12751743f;
    bf16x8 qf[4];
    {
        const int qrow = qbase + wq * 16 + col;
        const float* gQ = Q + ((size_t)b * NQ_ + qrow) * D_;
        #pragma unroll
        for (int c = 0; c < 4; ++c) {
            const float* pp = gQ + c * 32 + quad * 8;
            f32x4 a0 = *(const f32x4*)pp;
            f32x4 a1 = *(const f32x4*)(pp + 4);
            uint4v us;
            us[0] = f2bf2(a0[0] * qscale, a0[1] * qscale);
            us[1] = f2bf2(a0[2] * qscale, a0[3] * qscale);
            us[2] = f2bf2(a1[0] * qscale, a1[1] * qscale);
            us[3] = f2bf2(a1[2] * qscale, a1[3] * qscale);
            qf[c] = __builtin_bit_cast(bf16x8, us);
        }
    }

    // ---- accumulators: partial O over own key-half, full 128 dv; scalar l
    f32x4 o[8];
    #pragma unroll
    for (int d = 0; d < 8; ++d) o[d] = (f32x4){0.f, 0.f, 0.f, 0.f};
    float l_run = 0.f;

    const ushort* tKb = Kb  + (size_t)b * 32 * 8192;
    const ushort* tVb = Vtb + (size_t)b * 32 * 8192;

    #define ISSUE_DMA(KT, BUF)                                               \
        do {                                                                 \
            const ushort* gk = tKb + (size_t)(KT) * 8192;                    \
            const ushort* gv = tVb + (size_t)(KT) * 8192;                    \
            _Pragma("unroll")                                                \
            for (int i = 0; i < 2; ++i) {                                    \
                int off = (i * 512 + tid) * 8;                               \
                gl_lds16(gk + off, &KVbuf[BUF][off]);                        \
                gl_lds16(gv + off, &KVbuf[BUF][8192 + off]);                 \
            }                                                                \
        } while (0)

    ISSUE_DMA(0, 0);

    const int swz = col & 7;

    for (int kt = 0; kt < ntiles; ++kt) {
        const int buf = kt & 1;
        __syncthreads();   // drains DMA(kt); prev readers done
        if (kt + 1 < ntiles) ISSUE_DMA(kt + 1, buf ^ 1);

        const ushort* Kt = &KVbuf[buf][0];
        const ushort* Vt = &KVbuf[buf][8192];

        // ---- S^T = K Q^T (swapped): lane holds S[q=col][key=kc*16+quad*4+r]
        f32x4 s0 = (f32x4){0.f,0.f,0.f,0.f};
        f32x4 s1 = (f32x4){0.f,0.f,0.f,0.f};
        __builtin_amdgcn_s_setprio(1);
        {
            const int key0 = (wk * 32 + col) * 128;
            #pragma unroll
            for (int c = 0; c < 4; ++c) {
                bf16x8 kb = __builtin_bit_cast(bf16x8, *(const ushort8v*)
                    &Kt[key0 + (((c * 4 + quad) ^ swz) << 3)]);
                s0 = __builtin_amdgcn_mfma_f32_16x16x32_bf16(kb, qf[c], s0, 0, 0, 0);
            }
            #pragma unroll
            for (int c = 0; c < 4; ++c) {
                bf16x8 kb = __builtin_bit_cast(bf16x8, *(const ushort8v*)
                    &Kt[key0 + 16 * 128 + (((c * 4 + quad) ^ swz) << 3)]);
                s1 = __builtin_amdgcn_mfma_f32_16x16x32_bf16(kb, qf[c], s1, 0, 0, 0);
            }
        }
        __builtin_amdgcn_s_setprio(0);

        // ---- mask (key rows lane-indexed); exp2(-1e30) == 0
        const int rem = vl - kt * 64 - wk * 32;   // valid keys in this half
        if (rem < 32) {
            #pragma unroll
            for (int rr = 0; rr < 4; ++rr) {
                if (quad * 4 + rr >= rem)      s0[rr] = -1e30f;
                if (16 + quad * 4 + rr >= rem) s1[rr] = -1e30f;
            }
        }

        // ---- p = exp2(s) -> packed bf16; l sums the rounded values
        unsigned wA = f2bf2(exp2f(s0[0]), exp2f(s0[1]));
        unsigned wB = f2bf2(exp2f(s0[2]), exp2f(s0[3]));
        unsigned wC = f2bf2(exp2f(s1[0]), exp2f(s1[1]));
        unsigned wD = f2bf2(exp2f(s1[2]), exp2f(s1[3]));
        l_run += bfpair_sum(wA) + bfpair_sum(wB) + bfpair_sum(wC) + bfpair_sum(wD);

        // ---- in-register C-layout -> A-layout transpose across quads
        asm("v_permlane32_swap_b32 %0, %1" : "+v"(wA), "+v"(wC));
        asm("v_permlane32_swap_b32 %0, %1" : "+v"(wB), "+v"(wD));
        asm("v_permlane16_swap_b32 %0, %1" : "+v"(wA), "+v"(wC));
        asm("v_permlane16_swap_b32 %0, %1" : "+v"(wB), "+v"(wD));
        uint4v pw;
        pw[0] = wA; pw[1] = wB; pw[2] = wC; pw[3] = wD;
        bf16x8 pa = __builtin_bit_cast(bf16x8, pw);

        // ---- O_partial += P_own(16q x 32k) V_own(32k x 128dv)
        __builtin_amdgcn_s_setprio(1);
        #pragma unroll
        for (int dvc = 0; dvc < 8; ++dvc) {
            const int dv = dvc * 16 + col;
            bf16x8 vb = __builtin_bit_cast(bf16x8, *(const ushort8v*)
                &Vt[dv * 64 + (((wk * 4 + quad) ^ swz) << 3)]);
            o[dvc] = __builtin_amdgcn_mfma_f32_16x16x32_bf16(pa, vb, o[dvc], 0, 0, 0);
        }
        __builtin_amdgcn_s_setprio(0);
    }
    #undef ISSUE_DMA

    // ---- l: sum the 4 quads holding the same q=col
    l_run += __shfl_xor(l_run, 16, 64);
    l_run += __shfl_xor(l_run, 32, 64);

    __syncthreads();   // everyone done with KVbuf before aliasing as Osh

    if (L < 16) lsh[wk][wq * 16 + L] = l_run;
    #pragma unroll
    for (int dvc = 0; dvc < 8; ++dvc)
        #pragma unroll
        for (int rr = 0; rr < 4; ++rr)
            Osh[wk * 8192 + (wq * 16 + quad * 4 + rr) * 128 + dvc * 16 + col]
                = o[dvc][rr];
    __syncthreads();

    // ---- combine wk halves, normalize, coalesced store
    float* gO = Out + ((size_t)b * NQ_ + qbase) * DV_;
    #pragma unroll
    for (int i = 0; i < 4; ++i) {
        int idx = i * 512 + tid;           // f32x4 chunk id, row-major
        int row = idx >> 5;
        int dq  = idx & 31;
        f32x4 a0 = *(const f32x4*)&Osh[row * 128 + dq * 4];
        f32x4 a1 = *(const f32x4*)&Osh[8192 + row * 128 + dq * 4];
        float linv = 1.0f / (lsh[0][row] + lsh[1][row]);
        *(f32x4*)&gO[(size_t)row * DV_ + dq * 4] = (a0 + a1) * linv;
    }
}

extern "C" void kernel_launch(void* const* d_in, const int* in_sizes, int n_in,
                              void* d_out, int out_size, void* d_ws, size_t ws_size,
                              hipStream_t stream) {
    const float* Q  = (const float*)d_in[0];
    const float* K  = (const float*)d_in[1];
    const float* V  = (const float*)d_in[2];
    const int*   vl = (const int*)d_in[3];
    float* out = (float*)d_out;

    // ws: [0,4K) reserved | [4K, +8.39M) Kb | [next, +8.39M) Vtb  (~16.8 MB)
    char* ws = (char*)d_ws;
    ushort* Kbuf = (ushort*)(ws + 4096);
    ushort* Vbuf = Kbuf + (size_t)B_ * 32 * 8192;

    convert_kv<<<dim3(512, 1, 1), dim3(256, 1, 1), 0, stream>>>(K, V, vl, Kbuf, Vbuf);
    attn_fwd<<<dim3(NTASK_, 1, 1), dim3(512, 1, 1), 0, stream>>>(
        Q, vl, Kbuf, Vbuf, out);
}